// Round 1
// baseline (1082.681 us; speedup 1.0000x reference)
//
#include <hip/hip_runtime.h>

#define DI __device__ __forceinline__

typedef __attribute__((ext_vector_type(8))) short s16x8;
typedef __attribute__((ext_vector_type(4))) float f32x4;

DI f32x4 mfma16(s16x8 a, s16x8 b, f32x4 c) {
  return __builtin_amdgcn_mfma_f32_16x16x32_bf16(a, b, c, 0, 0, 0);
}

DI unsigned short f2bf(float f) {
  unsigned int u = __builtin_bit_cast(unsigned int, f);
  u += 0x7fffu + ((u >> 16) & 1u);
  return (unsigned short)(u >> 16);
}
DI float bf2f(unsigned short h) {
  unsigned int u = ((unsigned int)h) << 16;
  return __builtin_bit_cast(float, u);
}
DI void split2(float f, unsigned short &hi, unsigned short &lo) {
  hi = f2bf(f);
  lo = f2bf(f - bf2f(hi));
}
DI void write_pair4(unsigned short* hp, unsigned short* lp, float4 v) {
  unsigned short h0,h1,h2,h3,l0,l1,l2,l3;
  split2(v.x,h0,l0); split2(v.y,h1,l1); split2(v.z,h2,l2); split2(v.w,h3,l3);
  *(ushort4*)hp = make_ushort4(h0,h1,h2,h3);
  *(ushort4*)lp = make_ushort4(l0,l1,l2,l3);
}

// ---------------------------------------------------------------------------
// Split-K bf16x3 GEMM: C_partial[kidx][M][N] = A[M,K] @ B[N,K]^T  (128x128 tiles)
// ---------------------------------------------------------------------------
template<int M, int N, int K, int KS, bool SWZ>
__global__ __launch_bounds__(256, 2) void k_gemm(const float* __restrict__ A,
                                                 const float* __restrict__ Bw,
                                                 float* __restrict__ P) {
  constexpr int MT = M / 128, NT = N / 128;
  constexpr int KC = K / KS;
  constexpr int ITERS = KC / 32;
  int bid = blockIdx.x;
  int kidx, mt, nt;
  if (SWZ) {
    // gemm0 (MT=2,NT=8,KS=16): give each XCD whole k-chunks for x-slice L2 reuse
    int xcd = bid & 7, s = bid >> 3;
    kidx = xcd + 8 * (s >> 4);
    int mn = s & 15; mt = mn >> 3; nt = mn & 7;
  } else {
    kidx = bid / (MT * NT);
    int mn = bid % (MT * NT);
    mt = mn / NT; nt = mn % NT;
  }
  int tid = threadIdx.x;
  int w = tid >> 6, lane = tid & 63, q = lane >> 4, l15 = lane & 15;
  int wm = w >> 1, wn = w & 1;  // 2x2 wave grid, 64x64 wave tiles

  // frag-layout LDS: [k-quad][row][8 contiguous k]  (conflict-free b128 reads)
  __shared__ unsigned short Ah[4][128][8], Al[4][128][8];
  __shared__ unsigned short Bh[4][128][8], Bl[4][128][8];

  int srow = tid >> 1;            // 0..127
  int skb  = (tid & 1) * 16;      // 0 / 16
  const float* Abase = A  + (size_t)(mt * 128 + srow) * K + (size_t)kidx * KC;
  const float* Bbase = Bw + (size_t)(nt * 128 + srow) * K + (size_t)kidx * KC;

  float4 ra[4], rb[4];
  auto loadit = [&](int it) {
    const float* pa = Abase + it * 32 + skb;
    const float* pb = Bbase + it * 32 + skb;
#pragma unroll
    for (int i = 0; i < 4; i++) {
      ra[i] = *(const float4*)(pa + 4 * i);
      rb[i] = *(const float4*)(pb + 4 * i);
    }
  };

  f32x4 acc[4][4];
#pragma unroll
  for (int i = 0; i < 4; i++)
#pragma unroll
    for (int j = 0; j < 4; j++) acc[i][j] = (f32x4){0.f, 0.f, 0.f, 0.f};

  loadit(0);
  for (int it = 0; it < ITERS; ++it) {
    __syncthreads();
#pragma unroll
    for (int i = 0; i < 4; i++) {
      int k0 = skb + 4 * i, qq = k0 >> 3, j0 = k0 & 7;
      write_pair4(&Ah[qq][srow][j0], &Al[qq][srow][j0], ra[i]);
      write_pair4(&Bh[qq][srow][j0], &Bl[qq][srow][j0], rb[i]);
    }
    __syncthreads();
    if (it + 1 < ITERS) loadit(it + 1);  // prefetch overlaps MFMA below

    s16x8 afh[4], afl[4], bfh[4], bfl[4];
#pragma unroll
    for (int t = 0; t < 4; t++) {
      int m = wm * 64 + 16 * t + l15;
      afh[t] = *(const s16x8*)&Ah[q][m][0];
      afl[t] = *(const s16x8*)&Al[q][m][0];
      int n = wn * 64 + 16 * t + l15;
      bfh[t] = *(const s16x8*)&Bh[q][n][0];
      bfl[t] = *(const s16x8*)&Bl[q][n][0];
    }
#pragma unroll
    for (int ti = 0; ti < 4; ti++)
#pragma unroll
      for (int tj = 0; tj < 4; tj++) {
        acc[ti][tj] = mfma16(afh[ti], bfh[tj], acc[ti][tj]);
        acc[ti][tj] = mfma16(afl[ti], bfh[tj], acc[ti][tj]);
        acc[ti][tj] = mfma16(afh[ti], bfl[tj], acc[ti][tj]);
      }
  }
  // epilogue: D row = 4q+r (M), col = l15 (N)
#pragma unroll
  for (int ti = 0; ti < 4; ti++)
#pragma unroll
    for (int tj = 0; tj < 4; tj++)
#pragma unroll
      for (int r = 0; r < 4; r++) {
        int row = mt * 128 + wm * 64 + 16 * ti + 4 * q + r;
        int col = nt * 128 + wn * 64 + 16 * tj + l15;
        P[((size_t)kidx * M + row) * N + col] = acc[ti][tj][r];
      }
}

// ---------------------------------------------------------------------------
// Reduce split-K partials + batch-norm (batch stats) + leaky-relu
// (Linear bias cancels under BN: (h+b) - mean(h+b) == h - mean(h))
// ---------------------------------------------------------------------------
template<int KS, int N>
__global__ __launch_bounds__(256) void k_bn(const float* __restrict__ P,
                                            const float* __restrict__ g,
                                            const float* __restrict__ be,
                                            float* __restrict__ a) {
  int tid = threadIdx.x;
  int c = tid & 15, bg = tid >> 4;
  int col = blockIdx.x * 16 + c;
  __shared__ float hbuf[256][16];
  __shared__ float sbuf[16][16], s2buf[16][16];
  __shared__ float msc[16], msh[16];
  float s = 0.f, s2 = 0.f;
  for (int b = bg * 16; b < bg * 16 + 16; b++) {
    float h = 0.f;
#pragma unroll
    for (int kk = 0; kk < KS; kk++) h += P[((size_t)kk * 256 + b) * N + col];
    hbuf[b][c] = h;
    s += h; s2 += h * h;
  }
  sbuf[bg][c] = s; s2buf[bg][c] = s2;
  __syncthreads();
  if (bg == 0) {
    float ts = 0.f, ts2 = 0.f;
#pragma unroll
    for (int i = 0; i < 16; i++) { ts += sbuf[i][c]; ts2 += s2buf[i][c]; }
    float m = ts * (1.f / 256.f);
    float v = ts2 * (1.f / 256.f) - m * m;
    float rs = rsqrtf(v + 1e-5f);
    float sc = g[col] * rs;
    msc[c] = sc;
    msh[c] = be[col] - m * sc;
  }
  __syncthreads();
  float sc = msc[c], sh = msh[c];
  for (int b = bg * 16; b < bg * 16 + 16; b++) {
    float v = hbuf[b][c] * sc + sh;
    a[(size_t)b * N + col] = v > 0.f ? v : 0.01f * v;
  }
}

// ---------------------------------------------------------------------------
// Head: e=relu(P3sum+bout); mu/logvar; z=mu+eps*exp(0.5 lv); xp=z@Wih^T+bih
// one block per batch row, all row-local fp32.
// ---------------------------------------------------------------------------
__global__ __launch_bounds__(128) void k_head(const float* __restrict__ P3,
    const float* __restrict__ bout,
    const float* __restrict__ Wmu, const float* __restrict__ bmu,
    const float* __restrict__ Wlv, const float* __restrict__ blv,
    const float* __restrict__ Wih, const float* __restrict__ bih,
    const float* __restrict__ eps,
    float* __restrict__ out_mu, float* __restrict__ out_lv,
    float* __restrict__ xp) {
  int b = blockIdx.x, j = threadIdx.x;
  __shared__ float es[128], zs[128];
  float e = P3[(size_t)b * 128 + j] + P3[(size_t)(256 + b) * 128 + j] + bout[j];
  es[j] = e > 0.f ? e : 0.f;
  __syncthreads();
  float mu = bmu[j], lv = blv[j];
  for (int k = 0; k < 128; k++) {
    mu += es[k] * Wmu[j * 128 + k];
    lv += es[k] * Wlv[j * 128 + k];
  }
  out_mu[b * 128 + j] = mu;
  out_lv[b * 128 + j] = lv;
  float z = mu + eps[b * 128 + j] * expf(0.5f * lv);
  zs[j] = z;
  __syncthreads();
  for (int gi = 0; gi < 3; gi++) {
    int row = gi * 128 + j;
    float s = bih[row];
    for (int k = 0; k < 128; k++) s += zs[k] * Wih[row * 128 + k];
    xp[(size_t)b * 384 + row] = s;
  }
}

// ---------------------------------------------------------------------------
// GRU recurrence (phase A): 16 blocks x 16 batch; Whh as bf16 hi/lo MFMA
// fragments resident in VGPRs; h state in LDS as bf16 hi/lo; 128 steps.
// D = Whh_tile * h2^T : D[row 4q+r][batch l15]; writes all h states to H.
// ---------------------------------------------------------------------------
__global__ __launch_bounds__(256, 1) void k_gru(const float* __restrict__ Whh,
    const float* __restrict__ bhh, const float* __restrict__ xp,
    float* __restrict__ H) {
  int b0 = blockIdx.x * 16;
  int tid = threadIdx.x;
  int w = tid >> 6, lane = tid & 63, q = lane >> 4, l15 = lane & 15;
  __shared__ unsigned short h2hi[16][136], h2lo[16][136];  // pad 136 -> 2-way max

  int rb[6];
  rb[0] = 32 * w;        rb[1] = 32 * w + 16;
  rb[2] = 128 + 32 * w;  rb[3] = 128 + 32 * w + 16;
  rb[4] = 256 + 32 * w;  rb[5] = 256 + 32 * w + 16;

  // load weight fragments (A-operand: m=l15 row-in-tile, k = kt*32 + q*8 + j)
  s16x8 wfh[6][4], wfl[6][4];
#pragma unroll
  for (int t = 0; t < 6; t++)
#pragma unroll
    for (int kt = 0; kt < 4; kt++) {
      const float* p = Whh + (size_t)(rb[t] + l15) * 128 + kt * 32 + q * 8;
      s16x8 hi, lo;
#pragma unroll
      for (int j = 0; j < 8; j++) {
        unsigned short h, l; split2(p[j], h, l);
        hi[j] = (short)h; lo[j] = (short)l;
      }
      wfh[t][kt] = hi; wfl[t][kt] = lo;
    }

  int gb = b0 + l15;
  float xr_[2][4], xz_[2][4], xn_[2][4], bhn_[2][4], hprev[2][4];
#pragma unroll
  for (int t = 0; t < 2; t++)
#pragma unroll
    for (int r = 0; r < 4; r++) {
      int k0 = 32 * w + 16 * t + 4 * q + r;
      xr_[t][r] = xp[(size_t)gb * 384 + k0] + bhh[k0];
      xz_[t][r] = xp[(size_t)gb * 384 + 128 + k0] + bhh[128 + k0];
      xn_[t][r] = xp[(size_t)gb * 384 + 256 + k0];
      bhn_[t][r] = bhh[256 + k0];
      hprev[t][r] = 0.f;
    }

  for (int i = tid; i < 16 * 136; i += 256) {
    ((unsigned short*)h2hi)[i] = 0;
    ((unsigned short*)h2lo)[i] = 0;
  }
  __syncthreads();

  for (int s = 0; s < 128; s++) {
    // B-frags: B[k][n=batch l15], k = kt*32 + q*8 + j
    s16x8 bhf[4], blf[4];
#pragma unroll
    for (int kt = 0; kt < 4; kt++) {
      bhf[kt] = *(const s16x8*)&h2hi[l15][kt * 32 + q * 8];
      blf[kt] = *(const s16x8*)&h2lo[l15][kt * 32 + q * 8];
    }
    __syncthreads();  // all reads of step s done before step-s writes

    f32x4 acc[6];
#pragma unroll
    for (int t = 0; t < 6; t++) acc[t] = (f32x4){0.f, 0.f, 0.f, 0.f};
#pragma unroll
    for (int t = 0; t < 6; t++)
#pragma unroll
      for (int kt = 0; kt < 4; kt++) {
        acc[t] = mfma16(wfh[t][kt], bhf[kt], acc[t]);
        acc[t] = mfma16(wfl[t][kt], bhf[kt], acc[t]);
        acc[t] = mfma16(wfh[t][kt], blf[kt], acc[t]);
      }

#pragma unroll
    for (int t = 0; t < 2; t++) {
      unsigned short hs[4], ls[4];
#pragma unroll
      for (int r = 0; r < 4; r++) {
        float hr = acc[t][r], hz = acc[2 + t][r], hn = acc[4 + t][r];
        float rg = 1.f / (1.f + expf(-(xr_[t][r] + hr)));
        float zg = 1.f / (1.f + expf(-(xz_[t][r] + hz)));
        float ng = tanhf(xn_[t][r] + rg * (hn + bhn_[t][r]));
        float h2 = zg * (hprev[t][r] - ng) + ng;
        hprev[t][r] = h2;
        int k0 = 32 * w + 16 * t + 4 * q + r;
        H[((size_t)gb * 128 + s) * 128 + k0] = h2;
        split2(h2, hs[r], ls[r]);
      }
      int kb = 32 * w + 16 * t + 4 * q;
      *(ushort4*)&h2hi[l15][kb] = make_ushort4(hs[0], hs[1], hs[2], hs[3]);
      *(ushort4*)&h2lo[l15][kb] = make_ushort4(ls[0], ls[1], ls[2], ls[3]);
    }
    __syncthreads();
  }
}

// ---------------------------------------------------------------------------
// Phase B: logits = H @ Wfc^T + bfc, argmax (first-index tie-break), one-hot
// 512 blocks x 64 rows; bf16x3 MFMA; Wfc chunked through LDS.
// ---------------------------------------------------------------------------
__global__ __launch_bounds__(256, 2) void k_fc(const float* __restrict__ H,
    const float* __restrict__ Wfc, const float* __restrict__ bfc,
    float* __restrict__ out) {
  int rows0 = blockIdx.x * 64;
  int tid = threadIdx.x;
  int w = tid >> 6, lane = tid & 63, q = lane >> 4, l15 = lane & 15;
  __shared__ unsigned short Ah[4][4][64][8], Al[4][4][64][8];
  __shared__ unsigned short Bh[4][4][32][8], Bl[4][4][32][8];
  __shared__ int argbuf[64];

  // stage A (64 rows x 128 k)
  {
    int row = tid >> 2, kb = (tid & 3) * 32;
    const float* p = H + (size_t)(rows0 + row) * 128 + kb;
#pragma unroll
    for (int i = 0; i < 8; i++) {
      float4 v = *(const float4*)(p + 4 * i);
      int k0 = kb + 4 * i;
      int kt = k0 >> 5, qq = (k0 >> 3) & 3, j0 = k0 & 7;
      write_pair4(&Ah[kt][qq][row][j0], &Al[kt][qq][row][j0], v);
    }
  }
  __syncthreads();

  s16x8 afh[4], afl[4];
#pragma unroll
  for (int kt = 0; kt < 4; kt++) {
    afh[kt] = *(const s16x8*)&Ah[kt][q][16 * w + l15][0];
    afl[kt] = *(const s16x8*)&Al[kt][q][16 * w + l15][0];
  }

  float best[4]; int bidx[4];
#pragma unroll
  for (int r = 0; r < 4; r++) { best[r] = -3.4e38f; bidx[r] = 0; }

  for (int c = 0; c < 16; c++) {
    // stage B chunk: 32 vocab rows x 128 k
    {
      int n = tid >> 3, kb = (tid & 7) * 16;
      const float* p = Wfc + (size_t)(c * 32 + n) * 128 + kb;
#pragma unroll
      for (int i = 0; i < 4; i++) {
        float4 v = *(const float4*)(p + 4 * i);
        int k0 = kb + 4 * i;
        int kt = k0 >> 5, qq = (k0 >> 3) & 3, j0 = k0 & 7;
        write_pair4(&Bh[kt][qq][n][j0], &Bl[kt][qq][n][j0], v);
      }
    }
    __syncthreads();
    f32x4 acc[2];
    acc[0] = (f32x4){0.f, 0.f, 0.f, 0.f};
    acc[1] = (f32x4){0.f, 0.f, 0.f, 0.f};
#pragma unroll
    for (int nt = 0; nt < 2; nt++)
#pragma unroll
      for (int kt = 0; kt < 4; kt++) {
        s16x8 bh = *(const s16x8*)&Bh[kt][q][nt * 16 + l15][0];
        s16x8 bl = *(const s16x8*)&Bl[kt][q][nt * 16 + l15][0];
        acc[nt] = mfma16(afh[kt], bh, acc[nt]);
        acc[nt] = mfma16(afl[kt], bh, acc[nt]);
        acc[nt] = mfma16(afh[kt], bl, acc[nt]);
      }
#pragma unroll
    for (int nt = 0; nt < 2; nt++)
#pragma unroll
      for (int r = 0; r < 4; r++) {
        int col = c * 32 + nt * 16 + l15;
        float v = acc[nt][r] + bfc[col];
        if (v > best[r]) { best[r] = v; bidx[r] = col; }  // ascending cols => first-max kept
      }
    __syncthreads();  // frag reads done before next chunk overwrites LDS
  }

  // cross-lane argmax over l15 group (lanes with same q share rows)
#pragma unroll
  for (int r = 0; r < 4; r++) {
    float bv = best[r]; int bi = bidx[r];
    for (int off = 8; off >= 1; off >>= 1) {
      float ov = __shfl_xor(bv, off, 64);
      int oi = __shfl_xor(bi, off, 64);
      if (ov > bv || (ov == bv && oi < bi)) { bv = ov; bi = oi; }
    }
    if (l15 == 0) argbuf[16 * w + 4 * q + r] = bi;
  }
  __syncthreads();

  // race-free one-hot write
  int row = tid >> 2, cb = (tid & 3) * 128;
  int am = argbuf[row];
  float* op = out + (size_t)(rows0 + row) * 512 + cb;
#pragma unroll
  for (int i = 0; i < 32; i++) {
    float4 v = {0.f, 0.f, 0.f, 0.f};
    int base = cb + 4 * i;
    if (am >= base && am < base + 4) ((float*)&v)[am - base] = 1.0f;
    *(float4*)(op + 4 * i) = v;
  }
}

// ---------------------------------------------------------------------------
extern "C" void kernel_launch(void* const* d_in, const int* in_sizes, int n_in,
                              void* d_out, int out_size, void* d_ws, size_t ws_size,
                              hipStream_t stream) {
  const float* x    = (const float*)d_in[0];
  const float* eps  = (const float*)d_in[1];
  const float* W0   = (const float*)d_in[2];
  const float* g0   = (const float*)d_in[4];
  const float* be0  = (const float*)d_in[5];
  const float* W1   = (const float*)d_in[6];
  const float* g1   = (const float*)d_in[8];
  const float* be1  = (const float*)d_in[9];
  const float* W2   = (const float*)d_in[10];
  const float* g2   = (const float*)d_in[12];
  const float* be2  = (const float*)d_in[13];
  const float* Wout = (const float*)d_in[14];
  const float* bout = (const float*)d_in[15];
  const float* Wmu  = (const float*)d_in[16];
  const float* bmu  = (const float*)d_in[17];
  const float* Wlv  = (const float*)d_in[18];
  const float* blv  = (const float*)d_in[19];
  const float* Wih  = (const float*)d_in[20];
  const float* bih  = (const float*)d_in[21];
  const float* Whh  = (const float*)d_in[22];
  const float* bhh  = (const float*)d_in[23];
  const float* Wfc  = (const float*)d_in[24];
  const float* bfc  = (const float*)d_in[25];

  float* out    = (float*)d_out;
  float* mu_out = out + 16777216;
  float* lv_out = out + 16777216 + 32768;

  float* ws = (float*)d_ws;
  float* P0  = ws;                 // [16][256][1024] — aliased by H after BN0
  float* Hst = ws;                 // [256][128][128]
  float* a1  = ws + 4194304;       // [256][1024]
  float* P1  = a1 + 262144;        // [8][256][512]
  float* a2  = P1 + 1048576;       // [256][512]
  float* P2  = a2 + 131072;        // [4][256][256]
  float* a3  = P2 + 262144;        // [256][256]
  float* P3  = a3 + 65536;         // [2][256][128]
  float* xp  = P3 + 65536;         // [256][384]
  // total ws use: ~24.5 MB

  hipLaunchKernelGGL((k_gemm<256,1024,65536,16,true>), dim3(256), dim3(256), 0, stream, x,  W0,   P0);
  hipLaunchKernelGGL((k_bn<16,1024>),                  dim3(64),  dim3(256), 0, stream, P0, g0, be0, a1);
  hipLaunchKernelGGL((k_gemm<256,512,1024,8,false>),   dim3(64),  dim3(256), 0, stream, a1, W1,   P1);
  hipLaunchKernelGGL((k_bn<8,512>),                    dim3(32),  dim3(256), 0, stream, P1, g1, be1, a2);
  hipLaunchKernelGGL((k_gemm<256,256,512,4,false>),    dim3(16),  dim3(256), 0, stream, a2, W2,   P2);
  hipLaunchKernelGGL((k_bn<4,256>),                    dim3(16),  dim3(256), 0, stream, P2, g2, be2, a3);
  hipLaunchKernelGGL((k_gemm<256,128,256,2,false>),    dim3(4),   dim3(256), 0, stream, a3, Wout, P3);
  hipLaunchKernelGGL(k_head, dim3(256), dim3(128), 0, stream, P3, bout, Wmu, bmu, Wlv, blv, Wih, bih, eps, mu_out, lv_out, xp);
  hipLaunchKernelGGL(k_gru,  dim3(16),  dim3(256), 0, stream, Whh, bhh, xp, Hst);
  hipLaunchKernelGGL(k_fc,   dim3(512), dim3(256), 0, stream, Hst, Wfc, bfc, out);
}

// Round 2
// 975.013 us; speedup vs baseline: 1.1104x; 1.1104x over previous
//
#include <hip/hip_runtime.h>

#define DI __device__ __forceinline__

typedef __attribute__((ext_vector_type(8))) short s16x8;
typedef __attribute__((ext_vector_type(4))) float f32x4;

DI f32x4 mfma16(s16x8 a, s16x8 b, f32x4 c) {
  return __builtin_amdgcn_mfma_f32_16x16x32_bf16(a, b, c, 0, 0, 0);
}

DI unsigned short f2bf(float f) {
  unsigned int u = __builtin_bit_cast(unsigned int, f);
  u += 0x7fffu + ((u >> 16) & 1u);
  return (unsigned short)(u >> 16);
}
DI float bf2f(unsigned short h) {
  unsigned int u = ((unsigned int)h) << 16;
  return __builtin_bit_cast(float, u);
}
DI void split2(float f, unsigned short &hi, unsigned short &lo) {
  hi = f2bf(f);
  lo = f2bf(f - bf2f(hi));
}
DI void write_pair4(unsigned short* hp, unsigned short* lp, float4 v) {
  unsigned short h0,h1,h2,h3,l0,l1,l2,l3;
  split2(v.x,h0,l0); split2(v.y,h1,l1); split2(v.z,h2,l2); split2(v.w,h3,l3);
  *(ushort4*)hp = make_ushort4(h0,h1,h2,h3);
  *(ushort4*)lp = make_ushort4(l0,l1,l2,l3);
}

// ---------------------------------------------------------------------------
// Split-K bf16x3 GEMM, 128x128 tiles, double-buffered LDS (1 barrier/iter).
// P[kidx][M][N] partials.
// ---------------------------------------------------------------------------
template<int M, int N, int K, int KS, bool SWZ>
__global__ __launch_bounds__(256, 2) void k_gemm(const float* __restrict__ A,
                                                 const float* __restrict__ Bw,
                                                 float* __restrict__ P) {
  constexpr int MT = M / 128, NT = N / 128;
  constexpr int KC = K / KS;
  constexpr int ITERS = KC / 32;
  int bid = blockIdx.x;
  int kidx, mt, nt;
  if (SWZ) {
    // keep one kidx's 16 tiles on one XCD for x-slice L2 reuse
    int xcd = bid & 7, s = bid >> 3;
    kidx = xcd + 8 * (s >> 4);
    int mn = s & 15; mt = mn >> 3; nt = mn & 7;
  } else {
    kidx = bid / (MT * NT);
    int mn = bid % (MT * NT);
    mt = mn / NT; nt = mn % NT;
  }
  int tid = threadIdx.x;
  int w = tid >> 6, lane = tid & 63, q = lane >> 4, l15 = lane & 15;
  int wm = w >> 1, wn = w & 1;  // 2x2 wave grid, 64x64 wave tiles

  // double-buffered frag-layout LDS: [buf][k-quad][row][8 contiguous k]
  __shared__ unsigned short Ah[2][4][128][8], Al[2][4][128][8];
  __shared__ unsigned short Bh[2][4][128][8], Bl[2][4][128][8];

  int srow = tid >> 1;            // 0..127
  int skb  = (tid & 1) * 16;      // 0 / 16
  const float* Abase = A  + (size_t)(mt * 128 + srow) * K + (size_t)kidx * KC;
  const float* Bbase = Bw + (size_t)(nt * 128 + srow) * K + (size_t)kidx * KC;

  float4 ra[4], rb[4];
  auto loadit = [&](int it) {
    const float* pa = Abase + it * 32 + skb;
    const float* pb = Bbase + it * 32 + skb;
#pragma unroll
    for (int i = 0; i < 4; i++) {
      ra[i] = *(const float4*)(pa + 4 * i);
      rb[i] = *(const float4*)(pb + 4 * i);
    }
  };
  auto stage = [&](int pb) {
#pragma unroll
    for (int i = 0; i < 4; i++) {
      int k0 = skb + 4 * i, qq = k0 >> 3, j0 = k0 & 7;
      write_pair4(&Ah[pb][qq][srow][j0], &Al[pb][qq][srow][j0], ra[i]);
      write_pair4(&Bh[pb][qq][srow][j0], &Bl[pb][qq][srow][j0], rb[i]);
    }
  };

  f32x4 acc[4][4];
#pragma unroll
  for (int i = 0; i < 4; i++)
#pragma unroll
    for (int j = 0; j < 4; j++) acc[i][j] = (f32x4){0.f, 0.f, 0.f, 0.f};

  loadit(0);
  stage(0);
  loadit(1);

  for (int it = 0; it < ITERS; ++it) {
    __syncthreads();  // buf[it&1] writes visible; prior reads of buf[(it+1)&1] done
    if (it + 1 < ITERS) stage((it + 1) & 1);
    if (it + 2 < ITERS) loadit(it + 2);
    int pr = it & 1;

    s16x8 afh[4], afl[4], bfh[4], bfl[4];
#pragma unroll
    for (int t = 0; t < 4; t++) {
      int m = wm * 64 + 16 * t + l15;
      afh[t] = *(const s16x8*)&Ah[pr][q][m][0];
      afl[t] = *(const s16x8*)&Al[pr][q][m][0];
      int n = wn * 64 + 16 * t + l15;
      bfh[t] = *(const s16x8*)&Bh[pr][q][n][0];
      bfl[t] = *(const s16x8*)&Bl[pr][q][n][0];
    }
#pragma unroll
    for (int ti = 0; ti < 4; ti++)
#pragma unroll
      for (int tj = 0; tj < 4; tj++) {
        acc[ti][tj] = mfma16(afh[ti], bfh[tj], acc[ti][tj]);
        acc[ti][tj] = mfma16(afl[ti], bfh[tj], acc[ti][tj]);
        acc[ti][tj] = mfma16(afh[ti], bfl[tj], acc[ti][tj]);
      }
  }
  // epilogue: D row = 4q+r (M), col = l15 (N)
#pragma unroll
  for (int ti = 0; ti < 4; ti++)
#pragma unroll
    for (int tj = 0; tj < 4; tj++)
#pragma unroll
      for (int r = 0; r < 4; r++) {
        int row = mt * 128 + wm * 64 + 16 * ti + 4 * q + r;
        int col = nt * 128 + wn * 64 + 16 * tj + l15;
        P[((size_t)kidx * M + row) * N + col] = acc[ti][tj][r];
      }
}

// ---------------------------------------------------------------------------
// Coalesced split-K reduction for layer 0: O[idx] = sum_kk P[kk][idx]
// ---------------------------------------------------------------------------
template<int KS>
__global__ __launch_bounds__(256) void k_red(const float* __restrict__ P,
                                             float* __restrict__ O) {
  int idx = blockIdx.x * 256 + threadIdx.x;
  float s = 0.f;
#pragma unroll
  for (int kk = 0; kk < KS; kk++) s += P[(size_t)kk * 262144 + idx];
  O[idx] = s;
}

// ---------------------------------------------------------------------------
// Reduce split-K partials + batch-norm (batch stats) + leaky-relu
// (Linear bias cancels under BN)
// ---------------------------------------------------------------------------
template<int KS, int N>
__global__ __launch_bounds__(256) void k_bn(const float* __restrict__ P,
                                            const float* __restrict__ g,
                                            const float* __restrict__ be,
                                            float* __restrict__ a) {
  int tid = threadIdx.x;
  int c = tid & 15, bg = tid >> 4;
  int col = blockIdx.x * 16 + c;
  __shared__ float hbuf[256][16];
  __shared__ float sbuf[16][16], s2buf[16][16];
  __shared__ float msc[16], msh[16];
  float s = 0.f, s2 = 0.f;
  for (int b = bg * 16; b < bg * 16 + 16; b++) {
    float h = 0.f;
#pragma unroll
    for (int kk = 0; kk < KS; kk++) h += P[((size_t)kk * 256 + b) * N + col];
    hbuf[b][c] = h;
    s += h; s2 += h * h;
  }
  sbuf[bg][c] = s; s2buf[bg][c] = s2;
  __syncthreads();
  if (bg == 0) {
    float ts = 0.f, ts2 = 0.f;
#pragma unroll
    for (int i = 0; i < 16; i++) { ts += sbuf[i][c]; ts2 += s2buf[i][c]; }
    float m = ts * (1.f / 256.f);
    float v = ts2 * (1.f / 256.f) - m * m;
    float rs = rsqrtf(v + 1e-5f);
    float sc = g[col] * rs;
    msc[c] = sc;
    msh[c] = be[col] - m * sc;
  }
  __syncthreads();
  float sc = msc[c], sh = msh[c];
  for (int b = bg * 16; b < bg * 16 + 16; b++) {
    float v = hbuf[b][c] * sc + sh;
    a[(size_t)b * N + col] = v > 0.f ? v : 0.01f * v;
  }
}

// ---------------------------------------------------------------------------
// Head: e=relu(P3sum+bout); mu/logvar; z=mu+eps*exp(0.5 lv); xp=z@Wih^T+bih
// ---------------------------------------------------------------------------
__global__ __launch_bounds__(128) void k_head(const float* __restrict__ P3,
    const float* __restrict__ bout,
    const float* __restrict__ Wmu, const float* __restrict__ bmu,
    const float* __restrict__ Wlv, const float* __restrict__ blv,
    const float* __restrict__ Wih, const float* __restrict__ bih,
    const float* __restrict__ eps,
    float* __restrict__ out_mu, float* __restrict__ out_lv,
    float* __restrict__ xp) {
  int b = blockIdx.x, j = threadIdx.x;
  __shared__ float es[128], zs[128];
  float e = P3[(size_t)b * 128 + j] + P3[(size_t)(256 + b) * 128 + j] + bout[j];
  es[j] = e > 0.f ? e : 0.f;
  __syncthreads();
  float mu = bmu[j], lv = blv[j];
  for (int k = 0; k < 128; k++) {
    mu += es[k] * Wmu[j * 128 + k];
    lv += es[k] * Wlv[j * 128 + k];
  }
  out_mu[b * 128 + j] = mu;
  out_lv[b * 128 + j] = lv;
  float z = mu + eps[b * 128 + j] * expf(0.5f * lv);
  zs[j] = z;
  __syncthreads();
  for (int gi = 0; gi < 3; gi++) {
    int row = gi * 128 + j;
    float s = bih[row];
    for (int k = 0; k < 128; k++) s += zs[k] * Wih[row * 128 + k];
    xp[(size_t)b * 384 + row] = s;
  }
}

// ---------------------------------------------------------------------------
// GRU recurrence: 16 blocks x 16 batch; Whh bf16x3 frags resident in VGPRs;
// ping-pong h-state LDS (1 barrier/step); coalesced H store via LDS staging.
// ---------------------------------------------------------------------------
__global__ __launch_bounds__(256, 1) void k_gru(const float* __restrict__ Whh,
    const float* __restrict__ bhh, const float* __restrict__ xp,
    float* __restrict__ H) {
  int b0 = blockIdx.x * 16;
  int tid = threadIdx.x;
  int w = tid >> 6, lane = tid & 63, q = lane >> 4, l15 = lane & 15;
  __shared__ unsigned short h2hi[2][16][136], h2lo[2][16][136];
  __shared__ float hbuf[2][16][132];
  (void)lane;

  int rb6[6];
  rb6[0] = 32 * w;        rb6[1] = 32 * w + 16;
  rb6[2] = 128 + 32 * w;  rb6[3] = 128 + 32 * w + 16;
  rb6[4] = 256 + 32 * w;  rb6[5] = 256 + 32 * w + 16;

  // weight fragments (A-operand: m=l15 row-in-tile, k = kt*32 + q*8 + j)
  s16x8 wfh[6][4], wfl[6][4];
#pragma unroll
  for (int t = 0; t < 6; t++)
#pragma unroll
    for (int kt = 0; kt < 4; kt++) {
      const float* p = Whh + (size_t)(rb6[t] + l15) * 128 + kt * 32 + q * 8;
      s16x8 hi, lo;
#pragma unroll
      for (int j = 0; j < 8; j++) {
        unsigned short h, l; split2(p[j], h, l);
        hi[j] = (short)h; lo[j] = (short)l;
      }
      wfh[t][kt] = hi; wfl[t][kt] = lo;
    }

  int gb = b0 + l15;
  float xr_[2][4], xz_[2][4], xn_[2][4], bhn_[2][4], hprev[2][4];
#pragma unroll
  for (int t = 0; t < 2; t++)
#pragma unroll
    for (int r = 0; r < 4; r++) {
      int k0 = 32 * w + 16 * t + 4 * q + r;
      xr_[t][r] = xp[(size_t)gb * 384 + k0] + bhh[k0];
      xz_[t][r] = xp[(size_t)gb * 384 + 128 + k0] + bhh[128 + k0];
      xn_[t][r] = xp[(size_t)gb * 384 + 256 + k0];
      bhn_[t][r] = bhh[256 + k0];
      hprev[t][r] = 0.f;
    }

  for (int i = tid; i < 16 * 136; i += 256) {
    (&h2hi[0][0][0])[i] = 0;
    (&h2lo[0][0][0])[i] = 0;
  }
  __syncthreads();

  int hrow = tid >> 4, hcol = (tid & 15) * 8;

  for (int s = 0; s < 128; s++) {
    int p = s & 1;
    // B-frags: B[k][n=batch l15], k = kt*32 + q*8 + j  (state for step s)
    s16x8 bhf[4], blf[4];
#pragma unroll
    for (int kt = 0; kt < 4; kt++) {
      bhf[kt] = *(const s16x8*)&h2hi[p][l15][kt * 32 + q * 8];
      blf[kt] = *(const s16x8*)&h2lo[p][l15][kt * 32 + q * 8];
    }
    // coalesced store of previous step's h (overlaps with this step's MFMA)
    if (s > 0) {
      float4 v0 = *(const float4*)&hbuf[p ^ 1][hrow][hcol];
      float4 v1 = *(const float4*)&hbuf[p ^ 1][hrow][hcol + 4];
      float* dst = H + ((size_t)(b0 + hrow) * 128 + (s - 1)) * 128 + hcol;
      *(float4*)dst = v0;
      *(float4*)(dst + 4) = v1;
    }

    f32x4 acc[6];
#pragma unroll
    for (int t = 0; t < 6; t++) acc[t] = (f32x4){0.f, 0.f, 0.f, 0.f};
#pragma unroll
    for (int t = 0; t < 6; t++)
#pragma unroll
      for (int kt = 0; kt < 4; kt++) {
        acc[t] = mfma16(wfh[t][kt], bhf[kt], acc[t]);
        acc[t] = mfma16(wfl[t][kt], bhf[kt], acc[t]);
        acc[t] = mfma16(wfh[t][kt], blf[kt], acc[t]);
      }

#pragma unroll
    for (int t = 0; t < 2; t++) {
      unsigned short hs[4], ls[4];
      float hv[4];
#pragma unroll
      for (int r = 0; r < 4; r++) {
        float hr = acc[t][r], hz = acc[2 + t][r], hn = acc[4 + t][r];
        float rg = 1.f / (1.f + expf(-(xr_[t][r] + hr)));
        float zg = 1.f / (1.f + expf(-(xz_[t][r] + hz)));
        float ng = tanhf(xn_[t][r] + rg * (hn + bhn_[t][r]));
        float h2 = zg * (hprev[t][r] - ng) + ng;
        hprev[t][r] = h2;
        hv[r] = h2;
        split2(h2, hs[r], ls[r]);
      }
      int kb = 32 * w + 16 * t + 4 * q;
      *(float4*)&hbuf[p][l15][kb] = make_float4(hv[0], hv[1], hv[2], hv[3]);
      *(ushort4*)&h2hi[p ^ 1][l15][kb] = make_ushort4(hs[0], hs[1], hs[2], hs[3]);
      *(ushort4*)&h2lo[p ^ 1][l15][kb] = make_ushort4(ls[0], ls[1], ls[2], ls[3]);
    }
    __syncthreads();
  }
  // final step's h (s=127 wrote hbuf[1])
  {
    float4 v0 = *(const float4*)&hbuf[1][hrow][hcol];
    float4 v1 = *(const float4*)&hbuf[1][hrow][hcol + 4];
    float* dst = H + ((size_t)(b0 + hrow) * 128 + 127) * 128 + hcol;
    *(float4*)dst = v0;
    *(float4*)(dst + 4) = v1;
  }
}

// ---------------------------------------------------------------------------
// Phase B: logits = H @ Wfc^T + bfc, argmax (first-index), one-hot
// ---------------------------------------------------------------------------
__global__ __launch_bounds__(256, 2) void k_fc(const float* __restrict__ H,
    const float* __restrict__ Wfc, const float* __restrict__ bfc,
    float* __restrict__ out) {
  int rows0 = blockIdx.x * 64;
  int tid = threadIdx.x;
  int w = tid >> 6, lane = tid & 63, q = lane >> 4, l15 = lane & 15;
  __shared__ unsigned short Ah[4][4][64][8], Al[4][4][64][8];
  __shared__ unsigned short Bh[4][4][32][8], Bl[4][4][32][8];
  __shared__ int argbuf[64];
  (void)lane;

  // stage A (64 rows x 128 k)
  {
    int row = tid >> 2, kb = (tid & 3) * 32;
    const float* p = H + (size_t)(rows0 + row) * 128 + kb;
#pragma unroll
    for (int i = 0; i < 8; i++) {
      float4 v = *(const float4*)(p + 4 * i);
      int k0 = kb + 4 * i;
      int kt = k0 >> 5, qq = (k0 >> 3) & 3, j0 = k0 & 7;
      write_pair4(&Ah[kt][qq][row][j0], &Al[kt][qq][row][j0], v);
    }
  }
  __syncthreads();

  s16x8 afh[4], afl[4];
#pragma unroll
  for (int kt = 0; kt < 4; kt++) {
    afh[kt] = *(const s16x8*)&Ah[kt][q][16 * w + l15][0];
    afl[kt] = *(const s16x8*)&Al[kt][q][16 * w + l15][0];
  }

  float best[4]; int bidx[4];
#pragma unroll
  for (int r = 0; r < 4; r++) { best[r] = -3.4e38f; bidx[r] = 0; }

  for (int c = 0; c < 16; c++) {
    {
      int n = tid >> 3, kb = (tid & 7) * 16;
      const float* p = Wfc + (size_t)(c * 32 + n) * 128 + kb;
#pragma unroll
      for (int i = 0; i < 4; i++) {
        float4 v = *(const float4*)(p + 4 * i);
        int k0 = kb + 4 * i;
        int kt = k0 >> 5, qq = (k0 >> 3) & 3, j0 = k0 & 7;
        write_pair4(&Bh[kt][qq][n][j0], &Bl[kt][qq][n][j0], v);
      }
    }
    __syncthreads();
    f32x4 acc[2];
    acc[0] = (f32x4){0.f, 0.f, 0.f, 0.f};
    acc[1] = (f32x4){0.f, 0.f, 0.f, 0.f};
#pragma unroll
    for (int nt = 0; nt < 2; nt++)
#pragma unroll
      for (int kt = 0; kt < 4; kt++) {
        s16x8 bh = *(const s16x8*)&Bh[kt][q][nt * 16 + l15][0];
        s16x8 bl = *(const s16x8*)&Bl[kt][q][nt * 16 + l15][0];
        acc[nt] = mfma16(afh[kt], bh, acc[nt]);
        acc[nt] = mfma16(afl[kt], bh, acc[nt]);
        acc[nt] = mfma16(afh[kt], bl, acc[nt]);
      }
#pragma unroll
    for (int nt = 0; nt < 2; nt++)
#pragma unroll
      for (int r = 0; r < 4; r++) {
        int col = c * 32 + nt * 16 + l15;
        float v = acc[nt][r] + bfc[col];
        if (v > best[r]) { best[r] = v; bidx[r] = col; }
      }
    __syncthreads();
  }

#pragma unroll
  for (int r = 0; r < 4; r++) {
    float bv = best[r]; int bi = bidx[r];
    for (int off = 8; off >= 1; off >>= 1) {
      float ov = __shfl_xor(bv, off, 64);
      int oi = __shfl_xor(bi, off, 64);
      if (ov > bv || (ov == bv && oi < bi)) { bv = ov; bi = oi; }
    }
    if (l15 == 0) argbuf[16 * w + 4 * q + r] = bi;
  }
  __syncthreads();

  int row = tid >> 2, cb = (tid & 3) * 128;
  int am = argbuf[row];
  float* op = out + (size_t)(rows0 + row) * 512 + cb;
#pragma unroll
  for (int i = 0; i < 32; i++) {
    float4 v = {0.f, 0.f, 0.f, 0.f};
    int base = cb + 4 * i;
    if (am >= base && am < base + 4) ((float*)&v)[am - base] = 1.0f;
    *(float4*)(op + 4 * i) = v;
  }
}

// ---------------------------------------------------------------------------
extern "C" void kernel_launch(void* const* d_in, const int* in_sizes, int n_in,
                              void* d_out, int out_size, void* d_ws, size_t ws_size,
                              hipStream_t stream) {
  const float* x    = (const float*)d_in[0];
  const float* eps  = (const float*)d_in[1];
  const float* W0   = (const float*)d_in[2];
  const float* g0   = (const float*)d_in[4];
  const float* be0  = (const float*)d_in[5];
  const float* W1   = (const float*)d_in[6];
  const float* g1   = (const float*)d_in[8];
  const float* be1  = (const float*)d_in[9];
  const float* W2   = (const float*)d_in[10];
  const float* g2   = (const float*)d_in[12];
  const float* be2  = (const float*)d_in[13];
  const float* Wout = (const float*)d_in[14];
  const float* bout = (const float*)d_in[15];
  const float* Wmu  = (const float*)d_in[16];
  const float* bmu  = (const float*)d_in[17];
  const float* Wlv  = (const float*)d_in[18];
  const float* blv  = (const float*)d_in[19];
  const float* Wih  = (const float*)d_in[20];
  const float* bih  = (const float*)d_in[21];
  const float* Whh  = (const float*)d_in[22];
  const float* bhh  = (const float*)d_in[23];
  const float* Wfc  = (const float*)d_in[24];
  const float* bfc  = (const float*)d_in[25];

  float* out    = (float*)d_out;
  float* mu_out = out + 16777216;
  float* lv_out = out + 16777216 + 32768;

  // KS=64 path needs 75,890,688 B of workspace; fall back to KS=16 otherwise.
  const bool big = ws_size >= 75900000ull;
  const int KS0 = big ? 64 : 16;

  float* ws  = (float*)d_ws;
  float* P0  = ws;                        // [KS0][256][1024]
  float* O0  = ws + (size_t)262144 * KS0; // [256][1024]
  float* a1  = O0 + 262144;               // [256][1024]
  float* P1  = a1 + 262144;               // [8][256][512]
  float* a2  = P1 + 1048576;              // [256][512]
  float* P2  = a2 + 131072;               // [4][256][256]
  float* a3  = P2 + 262144;               // [256][256]
  float* P3  = a3 + 65536;                // [2][256][128]
  float* xp  = P3 + 65536;                // [256][384]
  float* Hst = ws;                        // [256][128][128] aliases P0 (dead)

  if (big) {
    hipLaunchKernelGGL((k_gemm<256,1024,65536,64,true>), dim3(1024), dim3(256), 0, stream, x, W0, P0);
    hipLaunchKernelGGL((k_red<64>),                      dim3(1024), dim3(256), 0, stream, P0, O0);
  } else {
    hipLaunchKernelGGL((k_gemm<256,1024,65536,16,true>), dim3(256),  dim3(256), 0, stream, x, W0, P0);
    hipLaunchKernelGGL((k_red<16>),                      dim3(1024), dim3(256), 0, stream, P0, O0);
  }
  hipLaunchKernelGGL((k_bn<1,1024>),                   dim3(64),  dim3(256), 0, stream, O0, g0, be0, a1);
  hipLaunchKernelGGL((k_gemm<256,512,1024,8,false>),   dim3(64),  dim3(256), 0, stream, a1, W1, P1);
  hipLaunchKernelGGL((k_bn<8,512>),                    dim3(32),  dim3(256), 0, stream, P1, g1, be1, a2);
  hipLaunchKernelGGL((k_gemm<256,256,512,4,false>),    dim3(16),  dim3(256), 0, stream, a2, W2, P2);
  hipLaunchKernelGGL((k_bn<4,256>),                    dim3(16),  dim3(256), 0, stream, P2, g2, be2, a3);
  hipLaunchKernelGGL((k_gemm<256,128,256,2,false>),    dim3(4),   dim3(256), 0, stream, a3, Wout, P3);
  hipLaunchKernelGGL(k_head, dim3(256), dim3(128), 0, stream, P3, bout, Wmu, bmu, Wlv, blv, Wih, bih, eps, mu_out, lv_out, xp);
  hipLaunchKernelGGL(k_gru,  dim3(16),  dim3(256), 0, stream, Whh, bhh, xp, Hst);
  hipLaunchKernelGGL(k_fc,   dim3(512), dim3(256), 0, stream, Hst, Wfc, bfc, out);
}

// Round 3
// 865.616 us; speedup vs baseline: 1.2508x; 1.1264x over previous
//
#include <hip/hip_runtime.h>

#define DI __device__ __forceinline__

typedef __attribute__((ext_vector_type(8))) short s16x8;
typedef __attribute__((ext_vector_type(4))) float f32x4;

DI f32x4 mfma16(s16x8 a, s16x8 b, f32x4 c) {
  return __builtin_amdgcn_mfma_f32_16x16x32_bf16(a, b, c, 0, 0, 0);
}

DI unsigned short f2bf(float f) {
  unsigned int u = __builtin_bit_cast(unsigned int, f);
  u += 0x7fffu + ((u >> 16) & 1u);
  return (unsigned short)(u >> 16);
}
DI float bf2f(unsigned short h) {
  unsigned int u = ((unsigned int)h) << 16;
  return __builtin_bit_cast(float, u);
}
DI void split2(float f, unsigned short &hi, unsigned short &lo) {
  hi = f2bf(f);
  lo = f2bf(f - bf2f(hi));
}
DI void write_pair4(unsigned short* hp, unsigned short* lp, float4 v) {
  unsigned short h0,h1,h2,h3,l0,l1,l2,l3;
  split2(v.x,h0,l0); split2(v.y,h1,l1); split2(v.z,h2,l2); split2(v.w,h3,l3);
  *(ushort4*)hp = make_ushort4(h0,h1,h2,h3);
  *(ushort4*)lp = make_ushort4(l0,l1,l2,l3);
}

// fast gates: v_exp_f32 + v_rcp_f32 (~3e-7 rel err; inside bf16x3 noise envelope)
DI float fsig(float x)  { return __builtin_amdgcn_rcpf(1.f + __expf(-x)); }
DI float ftanhf(float x){ return 1.f - 2.f * __builtin_amdgcn_rcpf(1.f + __expf(2.f * x)); }

// ---------------------------------------------------------------------------
// Split-K bf16x3 GEMM, 128x128 tiles, double-buffered LDS (1 barrier/iter).
// P[kidx][M][N] partials.
// ---------------------------------------------------------------------------
template<int M, int N, int K, int KS, bool SWZ>
__global__ __launch_bounds__(256, 2) void k_gemm(const float* __restrict__ A,
                                                 const float* __restrict__ Bw,
                                                 float* __restrict__ P) {
  constexpr int MT = M / 128, NT = N / 128;
  constexpr int KC = K / KS;
  constexpr int ITERS = KC / 32;
  int bid = blockIdx.x;
  int kidx, mt, nt;
  if (SWZ) {
    int xcd = bid & 7, s = bid >> 3;
    kidx = xcd + 8 * (s >> 4);
    int mn = s & 15; mt = mn >> 3; nt = mn & 7;
  } else {
    kidx = bid / (MT * NT);
    int mn = bid % (MT * NT);
    mt = mn / NT; nt = mn % NT;
  }
  int tid = threadIdx.x;
  int w = tid >> 6, lane = tid & 63, q = lane >> 4, l15 = lane & 15;
  int wm = w >> 1, wn = w & 1;

  __shared__ unsigned short Ah[2][4][128][8], Al[2][4][128][8];
  __shared__ unsigned short Bh[2][4][128][8], Bl[2][4][128][8];

  int srow = tid >> 1;
  int skb  = (tid & 1) * 16;
  const float* Abase = A  + (size_t)(mt * 128 + srow) * K + (size_t)kidx * KC;
  const float* Bbase = Bw + (size_t)(nt * 128 + srow) * K + (size_t)kidx * KC;

  float4 ra[4], rb[4];
  auto loadit = [&](int it) {
    const float* pa = Abase + it * 32 + skb;
    const float* pb = Bbase + it * 32 + skb;
#pragma unroll
    for (int i = 0; i < 4; i++) {
      ra[i] = *(const float4*)(pa + 4 * i);
      rb[i] = *(const float4*)(pb + 4 * i);
    }
  };
  auto stage = [&](int pb) {
#pragma unroll
    for (int i = 0; i < 4; i++) {
      int k0 = skb + 4 * i, qq = k0 >> 3, j0 = k0 & 7;
      write_pair4(&Ah[pb][qq][srow][j0], &Al[pb][qq][srow][j0], ra[i]);
      write_pair4(&Bh[pb][qq][srow][j0], &Bl[pb][qq][srow][j0], rb[i]);
    }
  };

  f32x4 acc[4][4];
#pragma unroll
  for (int i = 0; i < 4; i++)
#pragma unroll
    for (int j = 0; j < 4; j++) acc[i][j] = (f32x4){0.f, 0.f, 0.f, 0.f};

  loadit(0);
  stage(0);
  loadit(1);

  for (int it = 0; it < ITERS; ++it) {
    __syncthreads();
    if (it + 1 < ITERS) stage((it + 1) & 1);
    if (it + 2 < ITERS) loadit(it + 2);
    int pr = it & 1;

    s16x8 afh[4], afl[4], bfh[4], bfl[4];
#pragma unroll
    for (int t = 0; t < 4; t++) {
      int m = wm * 64 + 16 * t + l15;
      afh[t] = *(const s16x8*)&Ah[pr][q][m][0];
      afl[t] = *(const s16x8*)&Al[pr][q][m][0];
      int n = wn * 64 + 16 * t + l15;
      bfh[t] = *(const s16x8*)&Bh[pr][q][n][0];
      bfl[t] = *(const s16x8*)&Bl[pr][q][n][0];
    }
#pragma unroll
    for (int ti = 0; ti < 4; ti++)
#pragma unroll
      for (int tj = 0; tj < 4; tj++) {
        acc[ti][tj] = mfma16(afh[ti], bfh[tj], acc[ti][tj]);
        acc[ti][tj] = mfma16(afl[ti], bfh[tj], acc[ti][tj]);
        acc[ti][tj] = mfma16(afh[ti], bfl[tj], acc[ti][tj]);
      }
  }
#pragma unroll
  for (int ti = 0; ti < 4; ti++)
#pragma unroll
    for (int tj = 0; tj < 4; tj++)
#pragma unroll
      for (int r = 0; r < 4; r++) {
        int row = mt * 128 + wm * 64 + 16 * ti + 4 * q + r;
        int col = nt * 128 + wn * 64 + 16 * tj + l15;
        P[((size_t)kidx * M + row) * N + col] = acc[ti][tj][r];
      }
}

// ---------------------------------------------------------------------------
template<int KS>
__global__ __launch_bounds__(256) void k_red(const float* __restrict__ P,
                                             float* __restrict__ O) {
  int idx = blockIdx.x * 256 + threadIdx.x;
  float s = 0.f;
#pragma unroll
  for (int kk = 0; kk < KS; kk++) s += P[(size_t)kk * 262144 + idx];
  O[idx] = s;
}

// ---------------------------------------------------------------------------
template<int KS, int N>
__global__ __launch_bounds__(256) void k_bn(const float* __restrict__ P,
                                            const float* __restrict__ g,
                                            const float* __restrict__ be,
                                            float* __restrict__ a) {
  int tid = threadIdx.x;
  int c = tid & 15, bg = tid >> 4;
  int col = blockIdx.x * 16 + c;
  __shared__ float hbuf[256][16];
  __shared__ float sbuf[16][16], s2buf[16][16];
  __shared__ float msc[16], msh[16];
  float s = 0.f, s2 = 0.f;
  for (int b = bg * 16; b < bg * 16 + 16; b++) {
    float h = 0.f;
#pragma unroll
    for (int kk = 0; kk < KS; kk++) h += P[((size_t)kk * 256 + b) * N + col];
    hbuf[b][c] = h;
    s += h; s2 += h * h;
  }
  sbuf[bg][c] = s; s2buf[bg][c] = s2;
  __syncthreads();
  if (bg == 0) {
    float ts = 0.f, ts2 = 0.f;
#pragma unroll
    for (int i = 0; i < 16; i++) { ts += sbuf[i][c]; ts2 += s2buf[i][c]; }
    float m = ts * (1.f / 256.f);
    float v = ts2 * (1.f / 256.f) - m * m;
    float rs = rsqrtf(v + 1e-5f);
    float sc = g[col] * rs;
    msc[c] = sc;
    msh[c] = be[col] - m * sc;
  }
  __syncthreads();
  float sc = msc[c], sh = msh[c];
  for (int b = bg * 16; b < bg * 16 + 16; b++) {
    float v = hbuf[b][c] * sc + sh;
    a[(size_t)b * N + col] = v > 0.f ? v : 0.01f * v;
  }
}

// ---------------------------------------------------------------------------
__global__ __launch_bounds__(128) void k_head(const float* __restrict__ P3,
    const float* __restrict__ bout,
    const float* __restrict__ Wmu, const float* __restrict__ bmu,
    const float* __restrict__ Wlv, const float* __restrict__ blv,
    const float* __restrict__ Wih, const float* __restrict__ bih,
    const float* __restrict__ eps,
    float* __restrict__ out_mu, float* __restrict__ out_lv,
    float* __restrict__ xp) {
  int b = blockIdx.x, j = threadIdx.x;
  __shared__ float es[128], zs[128];
  float e = P3[(size_t)b * 128 + j] + P3[(size_t)(256 + b) * 128 + j] + bout[j];
  es[j] = e > 0.f ? e : 0.f;
  __syncthreads();
  float mu = bmu[j], lv = blv[j];
  for (int k = 0; k < 128; k++) {
    mu += es[k] * Wmu[j * 128 + k];
    lv += es[k] * Wlv[j * 128 + k];
  }
  out_mu[b * 128 + j] = mu;
  out_lv[b * 128 + j] = lv;
  float z = mu + eps[b * 128 + j] * expf(0.5f * lv);
  zs[j] = z;
  __syncthreads();
  for (int gi = 0; gi < 3; gi++) {
    int row = gi * 128 + j;
    float s = bih[row];
    for (int k = 0; k < 128; k++) s += zs[k] * Wih[row * 128 + k];
    xp[(size_t)b * 384 + row] = s;
  }
}

// ---------------------------------------------------------------------------
// GRU recurrence: 16 blocks x 16 batch; Whh bf16x3 frags resident in VGPRs;
// ping-pong h2 LDS; 9-slot LDS h ring -> one coalesced H burst per 8 steps
// (slot s%9 never collides with the 8 being flushed -> no extra barrier,
// vmcnt drain amortized 8x). Fast gates via v_exp/v_rcp.
// ---------------------------------------------------------------------------
__global__ __launch_bounds__(256, 1) void k_gru(const float* __restrict__ Whh,
    const float* __restrict__ bhh, const float* __restrict__ xp,
    float* __restrict__ H) {
  int b0 = blockIdx.x * 16;
  int tid = threadIdx.x;
  int w = tid >> 6, lane = tid & 63, q = lane >> 4, l15 = lane & 15;
  __shared__ unsigned short h2hi[2][16][136], h2lo[2][16][136];
  __shared__ float hstage[9][16][132];
  (void)lane;

  int rb6[6];
  rb6[0] = 32 * w;        rb6[1] = 32 * w + 16;
  rb6[2] = 128 + 32 * w;  rb6[3] = 128 + 32 * w + 16;
  rb6[4] = 256 + 32 * w;  rb6[5] = 256 + 32 * w + 16;

  // weight fragments (A-operand: m=l15 row-in-tile, k = kt*32 + q*8 + j)
  s16x8 wfh[6][4], wfl[6][4];
#pragma unroll
  for (int t = 0; t < 6; t++)
#pragma unroll
    for (int kt = 0; kt < 4; kt++) {
      const float* p = Whh + (size_t)(rb6[t] + l15) * 128 + kt * 32 + q * 8;
      s16x8 hi, lo;
#pragma unroll
      for (int j = 0; j < 8; j++) {
        unsigned short h, l; split2(p[j], h, l);
        hi[j] = (short)h; lo[j] = (short)l;
      }
      wfh[t][kt] = hi; wfl[t][kt] = lo;
    }

  int gb = b0 + l15;
  float xr_[2][4], xz_[2][4], xn_[2][4], bhn_[2][4], hprev[2][4];
#pragma unroll
  for (int t = 0; t < 2; t++)
#pragma unroll
    for (int r = 0; r < 4; r++) {
      int k0 = 32 * w + 16 * t + 4 * q + r;
      xr_[t][r] = xp[(size_t)gb * 384 + k0] + bhh[k0];
      xz_[t][r] = xp[(size_t)gb * 384 + 128 + k0] + bhh[128 + k0];
      xn_[t][r] = xp[(size_t)gb * 384 + 256 + k0];
      bhn_[t][r] = bhh[256 + k0];
      hprev[t][r] = 0.f;
    }

  for (int i = tid; i < 16 * 136; i += 256) {
    (&h2hi[0][0][0])[i] = 0;
    (&h2lo[0][0][0])[i] = 0;
  }
  __syncthreads();

  int hrow = tid >> 4, hcol = (tid & 15) * 8;
  int sl = 0;  // == s % 9

  for (int s = 0; s < 128; s++) {
    int p = s & 1;
    // B-frags for step s (prev h2), issued first
    s16x8 bhf[4], blf[4];
#pragma unroll
    for (int kt = 0; kt < 4; kt++) {
      bhf[kt] = *(const s16x8*)&h2hi[p][l15][kt * 32 + q * 8];
      blf[kt] = *(const s16x8*)&h2lo[p][l15][kt * 32 + q * 8];
    }
    // burst-flush previous 8 steps' h (overlaps B-frag latency + MFMA)
    if ((s & 7) == 0 && s) {
      int fb = s - 8;
#pragma unroll
      for (int ss = 0; ss < 8; ss++) {
        int t9 = sl + 1 + ss;           // (fb+ss) % 9
        int fsl = t9 >= 9 ? t9 - 9 : t9;
        float4 v0 = *(const float4*)&hstage[fsl][hrow][hcol];
        float4 v1 = *(const float4*)&hstage[fsl][hrow][hcol + 4];
        float* dst = H + ((size_t)(b0 + hrow) * 128 + fb + ss) * 128 + hcol;
        *(float4*)dst = v0;
        *(float4*)(dst + 4) = v1;
      }
    }

    // 12 independent MFMA chains (main + correction); t=0 gate tiles first
    f32x4 accm[6], accc[6];
#pragma unroll
    for (int t = 0; t < 6; t++) {
      accm[t] = (f32x4){0.f, 0.f, 0.f, 0.f};
      accc[t] = (f32x4){0.f, 0.f, 0.f, 0.f};
    }
    const int ord[6] = {0, 2, 4, 1, 3, 5};
#pragma unroll
    for (int oi = 0; oi < 6; oi++) {
      int t = ord[oi];
#pragma unroll
      for (int kt = 0; kt < 4; kt++) {
        accm[t] = mfma16(wfh[t][kt], bhf[kt], accm[t]);
        accc[t] = mfma16(wfl[t][kt], bhf[kt], accc[t]);
        accc[t] = mfma16(wfh[t][kt], blf[kt], accc[t]);
      }
    }

#pragma unroll
    for (int t = 0; t < 2; t++) {
      unsigned short hs[4], ls[4];
      float hv[4];
#pragma unroll
      for (int r = 0; r < 4; r++) {
        float hr = accm[t][r] + accc[t][r];
        float hz = accm[2 + t][r] + accc[2 + t][r];
        float hn = accm[4 + t][r] + accc[4 + t][r];
        float rg = fsig(xr_[t][r] + hr);
        float zg = fsig(xz_[t][r] + hz);
        float ng = ftanhf(fmaf(rg, hn + bhn_[t][r], xn_[t][r]));
        float h2 = fmaf(zg, hprev[t][r] - ng, ng);
        hprev[t][r] = h2;
        hv[r] = h2;
        split2(h2, hs[r], ls[r]);
      }
      int kb = 32 * w + 16 * t + 4 * q;
      *(float4*)&hstage[sl][l15][kb] = make_float4(hv[0], hv[1], hv[2], hv[3]);
      *(ushort4*)&h2hi[p ^ 1][l15][kb] = make_ushort4(hs[0], hs[1], hs[2], hs[3]);
      *(ushort4*)&h2lo[p ^ 1][l15][kb] = make_ushort4(ls[0], ls[1], ls[2], ls[3]);
    }
    sl = (sl == 8) ? 0 : sl + 1;
    __syncthreads();
  }
  // final flush: steps 120..127
#pragma unroll
  for (int ss = 0; ss < 8; ss++) {
    int fb = 120 + ss;
    int fsl = fb % 9;
    float4 v0 = *(const float4*)&hstage[fsl][hrow][hcol];
    float4 v1 = *(const float4*)&hstage[fsl][hrow][hcol + 4];
    float* dst = H + ((size_t)(b0 + hrow) * 128 + fb) * 128 + hcol;
    *(float4*)dst = v0;
    *(float4*)(dst + 4) = v1;
  }
}

// ---------------------------------------------------------------------------
// Phase B: logits = H @ Wfc^T + bfc, argmax (first-index), one-hot
// ---------------------------------------------------------------------------
__global__ __launch_bounds__(256, 2) void k_fc(const float* __restrict__ H,
    const float* __restrict__ Wfc, const float* __restrict__ bfc,
    float* __restrict__ out) {
  int rows0 = blockIdx.x * 64;
  int tid = threadIdx.x;
  int w = tid >> 6, lane = tid & 63, q = lane >> 4, l15 = lane & 15;
  __shared__ unsigned short Ah[4][4][64][8], Al[4][4][64][8];
  __shared__ unsigned short Bh[4][4][32][8], Bl[4][4][32][8];
  __shared__ int argbuf[64];
  (void)lane;

  {
    int row = tid >> 2, kb = (tid & 3) * 32;
    const float* p = H + (size_t)(rows0 + row) * 128 + kb;
#pragma unroll
    for (int i = 0; i < 8; i++) {
      float4 v = *(const float4*)(p + 4 * i);
      int k0 = kb + 4 * i;
      int kt = k0 >> 5, qq = (k0 >> 3) & 3, j0 = k0 & 7;
      write_pair4(&Ah[kt][qq][row][j0], &Al[kt][qq][row][j0], v);
    }
  }
  __syncthreads();

  s16x8 afh[4], afl[4];
#pragma unroll
  for (int kt = 0; kt < 4; kt++) {
    afh[kt] = *(const s16x8*)&Ah[kt][q][16 * w + l15][0];
    afl[kt] = *(const s16x8*)&Al[kt][q][16 * w + l15][0];
  }

  float best[4]; int bidx[4];
#pragma unroll
  for (int r = 0; r < 4; r++) { best[r] = -3.4e38f; bidx[r] = 0; }

  for (int c = 0; c < 16; c++) {
    {
      int n = tid >> 3, kb = (tid & 7) * 16;
      const float* p = Wfc + (size_t)(c * 32 + n) * 128 + kb;
#pragma unroll
      for (int i = 0; i < 4; i++) {
        float4 v = *(const float4*)(p + 4 * i);
        int k0 = kb + 4 * i;
        int kt = k0 >> 5, qq = (k0 >> 3) & 3, j0 = k0 & 7;
        write_pair4(&Bh[kt][qq][n][j0], &Bl[kt][qq][n][j0], v);
      }
    }
    __syncthreads();
    f32x4 acc[2];
    acc[0] = (f32x4){0.f, 0.f, 0.f, 0.f};
    acc[1] = (f32x4){0.f, 0.f, 0.f, 0.f};
#pragma unroll
    for (int nt = 0; nt < 2; nt++)
#pragma unroll
      for (int kt = 0; kt < 4; kt++) {
        s16x8 bh = *(const s16x8*)&Bh[kt][q][nt * 16 + l15][0];
        s16x8 bl = *(const s16x8*)&Bl[kt][q][nt * 16 + l15][0];
        acc[nt] = mfma16(afh[kt], bh, acc[nt]);
        acc[nt] = mfma16(afl[kt], bh, acc[nt]);
        acc[nt] = mfma16(afh[kt], bl, acc[nt]);
      }
#pragma unroll
    for (int nt = 0; nt < 2; nt++)
#pragma unroll
      for (int r = 0; r < 4; r++) {
        int col = c * 32 + nt * 16 + l15;
        float v = acc[nt][r] + bfc[col];
        if (v > best[r]) { best[r] = v; bidx[r] = col; }
      }
    __syncthreads();
  }

#pragma unroll
  for (int r = 0; r < 4; r++) {
    float bv = best[r]; int bi = bidx[r];
    for (int off = 8; off >= 1; off >>= 1) {
      float ov = __shfl_xor(bv, off, 64);
      int oi = __shfl_xor(bi, off, 64);
      if (ov > bv || (ov == bv && oi < bi)) { bv = ov; bi = oi; }
    }
    if (l15 == 0) argbuf[16 * w + 4 * q + r] = bi;
  }
  __syncthreads();

  int row = tid >> 2, cb = (tid & 3) * 128;
  int am = argbuf[row];
  float* op = out + (size_t)(rows0 + row) * 512 + cb;
#pragma unroll
  for (int i = 0; i < 32; i++) {
    float4 v = {0.f, 0.f, 0.f, 0.f};
    int base = cb + 4 * i;
    if (am >= base && am < base + 4) ((float*)&v)[am - base] = 1.0f;
    *(float4*)(op + 4 * i) = v;
  }
}

// ---------------------------------------------------------------------------
extern "C" void kernel_launch(void* const* d_in, const int* in_sizes, int n_in,
                              void* d_out, int out_size, void* d_ws, size_t ws_size,
                              hipStream_t stream) {
  const float* x    = (const float*)d_in[0];
  const float* eps  = (const float*)d_in[1];
  const float* W0   = (const float*)d_in[2];
  const float* g0   = (const float*)d_in[4];
  const float* be0  = (const float*)d_in[5];
  const float* W1   = (const float*)d_in[6];
  const float* g1   = (const float*)d_in[8];
  const float* be1  = (const float*)d_in[9];
  const float* W2   = (const float*)d_in[10];
  const float* g2   = (const float*)d_in[12];
  const float* be2  = (const float*)d_in[13];
  const float* Wout = (const float*)d_in[14];
  const float* bout = (const float*)d_in[15];
  const float* Wmu  = (const float*)d_in[16];
  const float* bmu  = (const float*)d_in[17];
  const float* Wlv  = (const float*)d_in[18];
  const float* blv  = (const float*)d_in[19];
  const float* Wih  = (const float*)d_in[20];
  const float* bih  = (const float*)d_in[21];
  const float* Whh  = (const float*)d_in[22];
  const float* bhh  = (const float*)d_in[23];
  const float* Wfc  = (const float*)d_in[24];
  const float* bfc  = (const float*)d_in[25];

  float* out    = (float*)d_out;
  float* mu_out = out + 16777216;
  float* lv_out = out + 16777216 + 32768;

  const bool big = ws_size >= 75900000ull;
  const int KS0 = big ? 64 : 16;

  float* ws  = (float*)d_ws;
  float* P0  = ws;
  float* O0  = ws + (size_t)262144 * KS0;
  float* a1  = O0 + 262144;
  float* P1  = a1 + 262144;
  float* a2  = P1 + 1048576;
  float* P2  = a2 + 131072;
  float* a3  = P2 + 262144;
  float* P3  = a3 + 65536;
  float* xp  = P3 + 65536;
  float* Hst = ws;  // aliases P0 (dead after k_red)

  if (big) {
    hipLaunchKernelGGL((k_gemm<256,1024,65536,64,true>), dim3(1024), dim3(256), 0, stream, x, W0, P0);
    hipLaunchKernelGGL((k_red<64>),                      dim3(1024), dim3(256), 0, stream, P0, O0);
  } else {
    hipLaunchKernelGGL((k_gemm<256,1024,65536,16,true>), dim3(256),  dim3(256), 0, stream, x, W0, P0);
    hipLaunchKernelGGL((k_red<16>),                      dim3(1024), dim3(256), 0, stream, P0, O0);
  }
  hipLaunchKernelGGL((k_bn<1,1024>),                   dim3(64),  dim3(256), 0, stream, O0, g0, be0, a1);
  hipLaunchKernelGGL((k_gemm<256,512,1024,8,false>),   dim3(64),  dim3(256), 0, stream, a1, W1, P1);
  hipLaunchKernelGGL((k_bn<8,512>),                    dim3(32),  dim3(256), 0, stream, P1, g1, be1, a2);
  hipLaunchKernelGGL((k_gemm<256,256,512,4,false>),    dim3(16),  dim3(256), 0, stream, a2, W2, P2);
  hipLaunchKernelGGL((k_bn<4,256>),                    dim3(16),  dim3(256), 0, stream, P2, g2, be2, a3);
  hipLaunchKernelGGL((k_gemm<256,128,256,2,false>),    dim3(4),   dim3(256), 0, stream, a3, Wout, P3);
  hipLaunchKernelGGL(k_head, dim3(256), dim3(128), 0, stream, P3, bout, Wmu, bmu, Wlv, blv, Wih, bih, eps, mu_out, lv_out, xp);
  hipLaunchKernelGGL(k_gru,  dim3(16),  dim3(256), 0, stream, Whh, bhh, xp, Hst);
  hipLaunchKernelGGL(k_fc,   dim3(512), dim3(256), 0, stream, Hst, Wfc, bfc, out);
}